// Round 2
// 730.105 us; speedup vs baseline: 1.1050x; 1.1050x over previous
//
#include <hip/hip_runtime.h>
#include <math.h>

// Problem dims
#define BATCH 8
#define CH 6
#define HW 4096
#define FF 9216
#define RC 48            // BATCH*CH rows
#define LOG2E 1.44269504088896340736f
#define LN100 4.6051701859880913680f

typedef unsigned short u16;
typedef __attribute__((ext_vector_type(4))) float f32x4;
// Guide-verified fragment type for mfma_f32_16x16x32_bf16: 8 bf16 as shorts.
typedef __attribute__((ext_vector_type(8))) short short8;
union F8 { uint4 u; short8 b; };

// split fp32 -> bf16 hi (round-to-nearest via +0x8000 trick) + bf16 lo of residual.
// hi+lo represents f to ~2^-18 relative; MFMA(Ah,Bh)+MFMA(Ah,Bl)+MFMA(Al,Bh)
// drops only the ~2^-18 Al*Bl term -> fp32-class GEMM accuracy.
__device__ __forceinline__ void split1(float f, unsigned& h, unsigned& l) {
    unsigned u = __float_as_uint(f);
    unsigned hb = (u + 0x8000u) & 0xffff0000u;   // rounded hi, as f32 bits
    h = hb >> 16;
    float r = f - __uint_as_float(hb);           // exact residual
    l = (__float_as_uint(r) + 0x8000u) >> 16;
}

// ---------------- prep: split feature -> bf16 hi/lo [48][9216]; build xT ----
__global__ __launch_bounds__(256) void prep_kernel(
    const float* __restrict__ x, const float* __restrict__ feature,
    u16* __restrict__ fHi, u16* __restrict__ fLo, float* __restrict__ xT)
{
    int i = blockIdx.x * 256 + threadIdx.x;
    if (i < FF * RC) {
        unsigned h, l;
        split1(feature[i], h, l);
        fHi[i] = (u16)h;
        fLo[i] = (u16)l;
    } else {
        int t = i - FF * RC;
        if (t < BATCH * HW * CH) {
            int c = t % CH;
            int n = (t / CH) & (HW - 1);
            int b = t / (HW * CH);
            xT[t] = x[((size_t)(b * CH + c)) * HW + n];
        }
    }
}

// ---------------- MFMA skinny GEMM: C[r][j] = sum_k A[r][k] * W[j][k] -------
// A: bf16 hi/lo [48][FF] row-major (L2-resident). W: fp32 [N][FF] row-major,
// streamed once from HBM and split to bf16 hi/lo in-register.
// Wave-independent: each wave owns 32 j-cols (2 j-tiles) x 48 rows (3 m-tiles),
// one K-chunk. No LDS, no barriers. Partials: part[(chunk*48 + r)*N + j].
// mfma_f32_16x16x32_bf16 fragments: A/B lane holds 8 contiguous-k elems,
// row/col = lane&15, kgroup = lane>>4. C/D: col = lane&15, row = (lane>>4)*4+q.
__global__ __launch_bounds__(128, 4) void gemm_mfma(
    const float* __restrict__ W, const u16* __restrict__ Ahi,
    const u16* __restrict__ Alo, float* __restrict__ part,
    int N, int kchunk)
{
    const int lane = threadIdx.x & 63;
    const int wv = threadIdx.x >> 6;          // 0..1
    const int col = lane & 15;
    const int kg = lane >> 4;                 // 0..3
    const int j0 = blockIdx.x * 64 + wv * 32;
    const int kbase = blockIdx.y * kchunk;
    const int ntiles = kchunk >> 5;

    f32x4 acc[2][3];
#pragma unroll
    for (int jt = 0; jt < 2; ++jt)
#pragma unroll
        for (int mt = 0; mt < 3; ++mt)
            acc[jt][mt] = (f32x4){0.f, 0.f, 0.f, 0.f};

    for (int t = 0; t < ntiles; ++t) {
        const int ko = kbase + t * 32 + kg * 8;
        // ---- A fragments (bf16 hi/lo, 16 B each, L2-hit) ----
        F8 aH[3], aL[3];
#pragma unroll
        for (int mt = 0; mt < 3; ++mt) {
            size_t off = (size_t)(mt * 16 + col) * FF + ko;
            aH[mt].u = *(const uint4*)(Ahi + off);
            aL[mt].u = *(const uint4*)(Alo + off);
        }
#pragma unroll
        for (int jt = 0; jt < 2; ++jt) {
            // ---- W fragment: 8 contiguous fp32 (32 B) of row j0+jt*16+col ----
            const float* wp = W + (size_t)(j0 + jt * 16 + col) * FF + ko;
            float4 w0 = *(const float4*)wp;
            float4 w1 = *(const float4*)(wp + 4);
            float f[8] = {w0.x, w0.y, w0.z, w0.w, w1.x, w1.y, w1.z, w1.w};
            unsigned hh[8], ll[8];
#pragma unroll
            for (int e = 0; e < 8; ++e) split1(f[e], hh[e], ll[e]);
            F8 bH, bL;
            bH.u = make_uint4(hh[0] | (hh[1] << 16), hh[2] | (hh[3] << 16),
                              hh[4] | (hh[5] << 16), hh[6] | (hh[7] << 16));
            bL.u = make_uint4(ll[0] | (ll[1] << 16), ll[2] | (ll[3] << 16),
                              ll[4] | (ll[5] << 16), ll[6] | (ll[7] << 16));
#pragma unroll
            for (int mt = 0; mt < 3; ++mt) {
                acc[jt][mt] = __builtin_amdgcn_mfma_f32_16x16x32_bf16(
                    aH[mt].b, bH.b, acc[jt][mt], 0, 0, 0);
                acc[jt][mt] = __builtin_amdgcn_mfma_f32_16x16x32_bf16(
                    aH[mt].b, bL.b, acc[jt][mt], 0, 0, 0);
                acc[jt][mt] = __builtin_amdgcn_mfma_f32_16x16x32_bf16(
                    aL[mt].b, bH.b, acc[jt][mt], 0, 0, 0);
            }
        }
    }

    // ---- store partials: part[(chunk*48 + r)*N + j], r = mt*16 + (lane>>4)*4+q
    const int r0 = (lane >> 4) * 4;
#pragma unroll
    for (int jt = 0; jt < 2; ++jt) {
        int j = j0 + jt * 16 + col;
#pragma unroll
        for (int mt = 0; mt < 3; ++mt) {
            float* dst = part + ((size_t)blockIdx.y * 48 + mt * 16 + r0) * N + j;
#pragma unroll
            for (int q = 0; q < 4; ++q) dst[(size_t)q * N] = acc[jt][mt][q];
        }
    }
}

// ------- reduce1: h[r][j] = relu(sum_c p1 + b1[j]) -> bf16 hi/lo [48][FF] ---
__global__ __launch_bounds__(256) void reduce_relu(
    const float* __restrict__ part, const float* __restrict__ bias,
    u16* __restrict__ hHi, u16* __restrict__ hLo)
{
    int i = blockIdx.x * 256 + threadIdx.x;   // over 48*9216, r*FF + j
    float s = 0.f;
#pragma unroll
    for (int c = 0; c < 8; ++c) s += part[(size_t)c * (RC * FF) + i];
    int j = i % FF;
    s = fmaxf(s + bias[j], 0.f);
    unsigned h, l;
    split1(s, h, l);
    hHi[i] = (u16)h;
    hLo[i] = (u16)l;
}

// ---- reduce2: fTs[b][m][c] = (sum_c p2 + b2[m]) * ls[m] * LOG2E -----------
__global__ __launch_bounds__(256) void reduce_scale(
    const float* __restrict__ part, const float* __restrict__ bias,
    const float* __restrict__ logit_scale, float* __restrict__ fTs)
{
    int i = blockIdx.x * 256 + threadIdx.x;   // over B*HW*CH, (b*HW+m)*CH+cc
    int cc = i % CH;
    int bm = i / CH;
    int m = bm & (HW - 1);
    int b = bm >> 12;
    float s = 0.f;
#pragma unroll
    for (int c = 0; c < 24; ++c)
        s += part[((size_t)c * RC + b * CH + cc) * HW + m];
    float lv = fminf(logit_scale[m], LN100);
    float ls = __builtin_amdgcn_exp2f(lv * LOG2E);
    fTs[i] = (s + bias[m]) * ls * LOG2E;
}

// ---------------- pass A: column sums D over an n-chunk --------------------
__global__ __launch_bounds__(256) void colsum_kernel(
    const float* __restrict__ fTs, const float* __restrict__ xT,
    float* __restrict__ Dpart)
{
    __shared__ float xs[512 * CH];   // 12 KB
    const int t = threadIdx.x;
    const int b = blockIdx.y;
    const int ns = blockIdx.z;
    {
        const float4* src = (const float4*)(xT + ((size_t)b * HW + ns * 512) * CH);
        float4* dst = (float4*)xs;
        dst[t]       = src[t];
        dst[t + 256] = src[t + 256];
        dst[t + 512] = src[t + 512];
    }
    __syncthreads();

    int m = blockIdx.x * 256 + t;
    const float2* f2 = (const float2*)(fTs + ((size_t)b * HW + m) * CH);
    float2 fa = f2[0], fb = f2[1], fc = f2[2];
    float s0 = fa.x, s1 = fa.y, s2 = fb.x, s3 = fb.y, s4 = fc.x, s5 = fc.y;

    float D = 0.f;
#pragma unroll 4
    for (int n = 0; n < 512; ++n) {
        const float* xn = xs + n * CH;   // wave-uniform -> LDS broadcast
        float a = fmaf(s0, xn[0], fmaf(s1, xn[1], fmaf(s2, xn[2],
                  fmaf(s3, xn[3], fmaf(s4, xn[4], s5 * xn[5])))));
        D += __builtin_amdgcn_exp2f(a);
    }
    Dpart[((size_t)b * 8 + ns) * HW + m] = D;
}

// ---- combine D -> write pre-scaled xR[b][m][c] = x[c,m] / D ---------------
__global__ __launch_bounds__(256) void combineD_kernel(
    const float* __restrict__ Dpart, const float* __restrict__ xT,
    float* __restrict__ xR)
{
    int i = blockIdx.x * 256 + threadIdx.x;
    if (i >= BATCH * HW) return;
    int b = i >> 12, m = i & (HW - 1);
    float s = 0.f;
    for (int ns = 0; ns < 8; ++ns) s += Dpart[((size_t)b * 8 + ns) * HW + m];
    float r = 1.0f / s;
    const float2* xs = (const float2*)(xT + (size_t)i * CH);
    float2 v0 = xs[0], v1 = xs[1], v2 = xs[2];
    float2* xd = (float2*)(xR + (size_t)i * CH);
    xd[0] = make_float2(v0.x * r, v0.y * r);
    xd[1] = make_float2(v1.x * r, v1.y * r);
    xd[2] = make_float2(v2.x * r, v2.y * r);
}

// -------- pass B: out[b,n,c] = LN( sum_m exp(t) * xR[m,c] ) ----------------
__global__ __launch_bounds__(256) void attn_out_kernel(
    const float* __restrict__ fTs, const float* __restrict__ xT,
    const float* __restrict__ xR, const float* __restrict__ nw,
    const float* __restrict__ nb, float* __restrict__ out)
{
    int b = blockIdx.y;
    int wv = threadIdx.x >> 6;
    int lane = threadIdx.x & 63;
    int n0 = (blockIdx.x * 4 + wv) * 8;

    const float* __restrict__ xb = xT + (size_t)b * HW * CH;
    float xn[8][6];
#pragma unroll
    for (int n = 0; n < 8; ++n)
#pragma unroll
        for (int c = 0; c < 6; ++c) xn[n][c] = xb[(size_t)(n0 + n) * CH + c];

    const float* __restrict__ frb = fTs + (size_t)b * HW * CH;
    const float* __restrict__ xrb = xR + (size_t)b * HW * CH;

    float acc[8][6];
#pragma unroll
    for (int n = 0; n < 8; ++n)
#pragma unroll
        for (int c = 0; c < 6; ++c) acc[n][c] = 0.f;

    for (int i = 0; i < 64; ++i) {
        int m = i * 64 + lane;
        const float2* f2 = (const float2*)(frb + (size_t)m * CH);
        float2 fa = f2[0], fb = f2[1], fc = f2[2];
        const float2* x2 = (const float2*)(xrb + (size_t)m * CH);
        float2 xa = x2[0], xb2 = x2[1], xc = x2[2];
        float f0 = fa.x, f1 = fa.y, f2v = fb.x, f3 = fb.y, f4 = fc.x, f5 = fc.y;
#pragma unroll
        for (int n = 0; n < 8; ++n) {
            float a = fmaf(f0, xn[n][0], fmaf(f1, xn[n][1], fmaf(f2v, xn[n][2],
                      fmaf(f3, xn[n][3], fmaf(f4, xn[n][4], f5 * xn[n][5])))));
            float p = __builtin_amdgcn_exp2f(a);
            acc[n][0] = fmaf(p, xa.x, acc[n][0]);
            acc[n][1] = fmaf(p, xa.y, acc[n][1]);
            acc[n][2] = fmaf(p, xb2.x, acc[n][2]);
            acc[n][3] = fmaf(p, xb2.y, acc[n][3]);
            acc[n][4] = fmaf(p, xc.x, acc[n][4]);
            acc[n][5] = fmaf(p, xc.y, acc[n][5]);
        }
    }

    // butterfly reduce across the 64 lanes
#pragma unroll
    for (int n = 0; n < 8; ++n)
#pragma unroll
        for (int c = 0; c < 6; ++c) {
            float v = acc[n][c];
            for (int d = 1; d < 64; d <<= 1) v += __shfl_xor(v, d, 64);
            acc[n][c] = v;
        }

    if (lane == 0) {
        float wc[6], bc[6];
#pragma unroll
        for (int c = 0; c < 6; ++c) { wc[c] = nw[c]; bc[c] = nb[c]; }
#pragma unroll
        for (int n = 0; n < 8; ++n) {
            float mu = (acc[n][0] + acc[n][1] + acc[n][2] +
                        acc[n][3] + acc[n][4] + acc[n][5]) * (1.f / 6.f);
            float var = 0.f;
#pragma unroll
            for (int c = 0; c < 6; ++c) {
                float dv = acc[n][c] - mu;
                var = fmaf(dv, dv, var);
            }
            var *= (1.f / 6.f);
            float inv = rsqrtf(var + 1e-5f);
#pragma unroll
            for (int c = 0; c < 6; ++c)
                out[((size_t)(b * CH + c)) * HW + n0 + n] =
                    (acc[n][c] - mu) * inv * wc[c] + bc[c];
        }
    }
}

// ---------------------------------------------------------------------------
extern "C" void kernel_launch(void* const* d_in, const int* in_sizes, int n_in,
                              void* d_out, int out_size, void* d_ws, size_t ws_size,
                              hipStream_t stream)
{
    const float* x           = (const float*)d_in[0];
    const float* feature     = (const float*)d_in[1];
    const float* fc1_w       = (const float*)d_in[2];
    const float* fc1_b       = (const float*)d_in[3];
    const float* fc2_w       = (const float*)d_in[4];
    const float* fc2_b       = (const float*)d_in[5];
    const float* logit_scale = (const float*)d_in[6];
    const float* norm_w      = (const float*)d_in[7];
    const float* norm_b      = (const float*)d_in[8];
    float* out = (float*)d_out;

    // workspace layout
    u16* fHi = (u16*)d_ws;                    // 442368 u16
    u16* fLo = fHi + 442368;                  // 442368 u16
    u16* hHi = fLo + 442368;                  // 442368 u16
    u16* hLo = hHi + 442368;                  // 442368 u16  (-> 3,538,944 B)
    float* part = (float*)(hLo + 442368);     // max(8*442368, 24*196608) = 4,718,592 f
    float* fTs   = part + 4718592;            // 196608 f
    float* xT    = fTs + 196608;              // 196608 f
    float* Dpart = xT + 196608;               // 262144 f
    float* xR    = Dpart + 262144;            // 196608 f
    // total ~25.8 MB

    // 1) split feature to bf16 hi/lo; build xT
    prep_kernel<<<2496, 256, 0, stream>>>(x, feature, fHi, fLo, xT);
    // 2) fc1: N=9216, K=9216, 8 k-chunks of 1152; 144 j-blocks of 64 cols
    gemm_mfma<<<dim3(144, 8), 128, 0, stream>>>(fc1_w, fHi, fLo, part, FF, 1152);
    // 3) reduce + bias + relu -> h hi/lo [48][9216]
    reduce_relu<<<1728, 256, 0, stream>>>(part, fc1_b, hHi, hLo);
    // 4) fc2: N=4096, K=9216, 24 k-chunks of 384; 64 j-blocks
    gemm_mfma<<<dim3(64, 24), 128, 0, stream>>>(fc2_w, hHi, hLo, part, HW, 384);
    // 5) reduce + bias + logit-scale fold -> fTs[b][m][c]
    reduce_scale<<<768, 256, 0, stream>>>(part, fc2_b, logit_scale, fTs);
    // 6) column sums of exp(t) over n (8 n-chunks)
    colsum_kernel<<<dim3(16, BATCH, 8), 256, 0, stream>>>(fTs, xT, Dpart);
    // 7) combine to reciprocal, fold into xR
    combineD_kernel<<<(BATCH * HW + 255) / 256, 256, 0, stream>>>(Dpart, xT, xR);
    // 8) attention output + LayerNorm, writes [B][C][HW]
    attn_out_kernel<<<dim3(128, BATCH), 256, 0, stream>>>(fTs, xT, xR, norm_w, norm_b, out);
}